// Round 12
// baseline (330.960 us; speedup 1.0000x reference)
//
#include <hip/hip_runtime.h>
#include <hip/hip_bf16.h>

#define N_NODES 50000
#define E_EDGES 800000
#define HID 128
#define HEADS 4
#define NEG_SLOPE 0.2f
#define LN_EPS 1e-5f
#define PARAM_FLOATS 17024  // [W region](16384) al(128) ar(128) b(128) g(128) be(128)
#define NBUCK 196           // buckets of 256 nodes
#define BCAP 6144           // max edges/bucket
#define BIN_CH 2048         // edges per bin block

typedef __attribute__((ext_vector_type(8))) short short8;
typedef __attribute__((ext_vector_type(4))) float float4v;

__device__ __forceinline__ float bf2f(__hip_bfloat16 b) { return __bfloat162float(b); }
__device__ __forceinline__ float u2f(unsigned short u) {
    return __uint_as_float(((unsigned int)u) << 16);
}
__device__ __forceinline__ short bfb(float f) {
    __hip_bfloat16 h = __float2bfloat16(f);
    return *(short*)&h;
}
__device__ __forceinline__ float leaky(float v) { return v > 0.f ? v : v * NEG_SLOPE; }

__device__ __forceinline__ unsigned int f2ord(float f) {
    unsigned int u = __float_as_uint(f);
    return (u & 0x80000000u) ? ~u : (u | 0x80000000u);
}
__device__ __forceinline__ float ord2f(unsigned int u) {
    u = (u & 0x80000000u) ? (u & 0x7FFFFFFFu) : ~u;
    return __uint_as_float(u);
}

// ---------- runtime dtype detection + gmax init ----------
__global__ __launch_bounds__(256) void detect_kernel(const unsigned int* __restrict__ w0,
                                                     unsigned int* __restrict__ flag,
                                                     unsigned int* __restrict__ gmax0,
                                                     unsigned int* __restrict__ gmax1) {
    int t = threadIdx.x;
    if (t < 4) {
        gmax0[t] = f2ord(-INFINITY);
        gmax1[t] = f2ord(-INFINITY);
    }
    int cnt = 0;
    for (int i = t; i < 4096; i += 256) {
        unsigned int lo = (w0[i] & 0xFFFFu) << 16;
        float v = fabsf(__uint_as_float(lo));
        if (v >= 1e-6f && v <= 1.0f) cnt++;
    }
    __shared__ int sh[4];
#pragma unroll
    for (int off = 32; off >= 1; off >>= 1) cnt += __shfl_xor(cnt, off);
    if ((t & 63) == 0) sh[t >> 6] = cnt;
    __syncthreads();
    if (t == 0) *flag = ((sh[0] + sh[1] + sh[2] + sh[3]) > 2048) ? 1u : 0u;
}

__device__ __forceinline__ float load_any(const void* p, int i, unsigned int isbf16) {
    return isbf16 ? bf2f(((const __hip_bfloat16*)p)[i]) : ((const float*)p)[i];
}

// params fp32 block (al/ar/b/g/be at 16384..17024) + Wt bf16 [n][k]
__global__ __launch_bounds__(256) void cvt_params_kernel(const void* W, const void* al,
                                                         const void* ar, const void* b,
                                                         const void* g, const void* be,
                                                         const unsigned int* __restrict__ flag,
                                                         float* __restrict__ out,
                                                         unsigned short* __restrict__ wt) {
    int i = blockIdx.x * 256 + threadIdx.x;
    if (i >= PARAM_FLOATS) return;
    unsigned int isb = *flag;
    if (i < 16384) {
        unsigned short bits;
        if (isb) bits = ((const unsigned short*)W)[i];
        else     { short s = bfb(((const float*)W)[i]); bits = (unsigned short)s; }
        wt[((i & 127) << 7) | (i >> 7)] = bits;  // Wt[n][k] = W[k][n]
        return;
    }
    const void* src; int off;
    if (i < 16512)      { src = al; off = i - 16384; }
    else if (i < 16640) { src = ar; off = i - 16512; }
    else if (i < 16768) { src = b;  off = i - 16640; }
    else if (i < 16896) { src = g;  off = i - 16768; }
    else                { src = be; off = i - 16896; }
    out[i] = load_any(src, off, isb);
}

// ---------- CSR build, phase 1: bin edges by dst>>8, packed (src<<8)|(dst&255) ----------
__global__ __launch_bounds__(256) void bin_kernel(const int* __restrict__ src,
                                                  const int* __restrict__ dst,
                                                  int* __restrict__ bcnt,
                                                  unsigned int* __restrict__ ebuf) {
    __shared__ int lh[NBUCK];
    __shared__ int lbase[NBUCK];
    int t = threadIdx.x;
    for (int i = t; i < NBUCK; i += 256) lh[i] = 0;
    __syncthreads();
    int e0 = blockIdx.x * BIN_CH;
    int n = min(BIN_CH, E_EDGES - e0);
    int s8[8], d8[8], rk[8];
#pragma unroll
    for (int j = 0; j < 8; ++j) {
        int k = j * 256 + t;
        if (k < n) {
            s8[j] = src[e0 + k];
            d8[j] = dst[e0 + k];
            rk[j] = atomicAdd(&lh[d8[j] >> 8], 1);
        }
    }
    __syncthreads();
    for (int i = t; i < NBUCK; i += 256) lbase[i] = atomicAdd(&bcnt[i], lh[i]);
    __syncthreads();
#pragma unroll
    for (int j = 0; j < 8; ++j) {
        int k = j * 256 + t;
        if (k < n) {
            int b = d8[j] >> 8;
            int pos = lbase[b] + rk[j];
            if (pos < BCAP)
                ebuf[b * BCAP + pos] = ((unsigned int)s8[j] << 8) | (unsigned int)(d8[j] & 255);
        }
    }
}

__global__ __launch_bounds__(256) void bscan_kernel(const int* __restrict__ bcnt,
                                                    int* __restrict__ bbase) {
    int t = threadIdx.x;
    int lane = t & 63, wid = t >> 6;
    int v = (t < NBUCK) ? min(bcnt[t], BCAP) : 0;
    int x = v;
#pragma unroll
    for (int o = 1; o < 64; o <<= 1) {
        int y = __shfl_up(x, o);
        if (lane >= o) x += y;
    }
    __shared__ int wt[4];
    if (lane == 63) wt[wid] = x;
    __syncthreads();
    int add = 0;
    for (int j = 0; j < wid; j++) add += wt[j];
    if (t < NBUCK) bbase[t] = add + x - v;  // exclusive
}

__global__ __launch_bounds__(256) void csr_kernel(const int* __restrict__ bcnt,
                                                  const int* __restrict__ bbase,
                                                  const unsigned int* __restrict__ ebuf,
                                                  int* __restrict__ offs,
                                                  int* __restrict__ esrc) {
    __shared__ int cnt[256];
    __shared__ int wt[4];
    __shared__ int out_lds[BCAP];
    int b = blockIdx.x, t = threadIdx.x;
    int n = min(bcnt[b], BCAP);
    int base = bbase[b];
    const unsigned int* eb = ebuf + b * BCAP;
    cnt[t] = 0;
    __syncthreads();
    for (int i = t; i < n; i += 256) atomicAdd(&cnt[eb[i] & 255u], 1);
    __syncthreads();
    int lane = t & 63, wid = t >> 6;
    int v = cnt[t];
    int x = v;
#pragma unroll
    for (int o = 1; o < 64; o <<= 1) {
        int y = __shfl_up(x, o);
        if (lane >= o) x += y;
    }
    if (lane == 63) wt[wid] = x;
    __syncthreads();
    int add = 0;
    for (int j = 0; j < wid; j++) add += wt[j];
    int excl = add + x - v;
    int node = b * 256 + t;
    if (node <= N_NODES) offs[node] = base + excl;
    __syncthreads();
    cnt[t] = excl;
    __syncthreads();
    for (int i = t; i < n; i += 256) {
        unsigned int e = eb[i];
        int p = atomicAdd(&cnt[e & 255u], 1);
        out_lds[p] = (int)(e >> 8);
    }
    __syncthreads();
    for (int i = t; i < n; i += 256) esrc[base + i] = out_lds[i];
}

// ---------- MFMA GEMM: h = x @ W -> bf16 h, el/er, per-head global el-max ----------
__global__ __launch_bounds__(256) void gemm_mfma_kernel(const void* __restrict__ xin,
                                                        const unsigned short* __restrict__ wt,
                                                        const float* __restrict__ params,
                                                        const unsigned int* __restrict__ flag,
                                                        int mode,
                                                        unsigned int* __restrict__ hb2,
                                                        float* __restrict__ el,
                                                        float* __restrict__ er,
                                                        unsigned int* __restrict__ gmax,
                                                        int M) {
    __shared__ float ldsC[4][16][132];
    __shared__ unsigned int smax[4];
    unsigned int isb = mode ? 1u : *flag;
    int t = threadIdx.x;
    if (t < 4) smax[t] = 0u;
    int w = t >> 6, lane = t & 63;
    int m = lane & 15, quad = lane >> 4;
    int row0b = blockIdx.x * 64;
    int arow = row0b + w * 16 + m;
    bool avalid = arow < M;

    float4v acc[8];
#pragma unroll
    for (int i = 0; i < 8; i++) acc[i] = (float4v){0.f, 0.f, 0.f, 0.f};

#pragma unroll
    for (int kt = 0; kt < 4; ++kt) {
        short8 a = (short8){0, 0, 0, 0, 0, 0, 0, 0};
        if (avalid) {
            int base = arow * 128 + kt * 32 + quad * 8;
            if (isb) {
                a = *(const short8*)((const unsigned short*)xin + base);
            } else {
                const float* xp = (const float*)xin + base;
                float4 f0 = *(const float4*)xp;
                float4 f1 = *(const float4*)(xp + 4);
                a = (short8){bfb(f0.x), bfb(f0.y), bfb(f0.z), bfb(f0.w),
                             bfb(f1.x), bfb(f1.y), bfb(f1.z), bfb(f1.w)};
            }
        }
#pragma unroll
        for (int ct = 0; ct < 8; ++ct) {
            short8 b = *(const short8*)(wt + (ct * 16 + m) * 128 + kt * 32 + quad * 8);
            acc[ct] = __builtin_amdgcn_mfma_f32_16x16x32_bf16(a, b, acc[ct], 0, 0, 0);
        }
    }

#pragma unroll
    for (int ct = 0; ct < 8; ++ct)
#pragma unroll
        for (int r = 0; r < 4; ++r)
            ldsC[w][quad * 4 + r][ct * 16 + m] = acc[ct][r];
    __syncthreads();

    int c0 = (t & 15) * 8;
    int r0e = (t >> 4) * 4;
    float al8[8], ar8[8];
#pragma unroll
    for (int j = 0; j < 8; j++) {
        al8[j] = params[16384 + c0 + j];
        ar8[j] = params[16512 + c0 + j];
    }
    int head = (lane & 15) >> 2;
    float elmax = -INFINITY;

#pragma unroll
    for (int i = 0; i < 4; i++) {
        int rr = r0e + i;
        int row = row0b + rr;
        bool ok = row < M;
        const float* ld = &ldsC[rr >> 4][rr & 15][c0];
        float4 h0 = *(const float4*)ld;
        float4 h1 = *(const float4*)(ld + 4);
        float hv[8] = {h0.x, h0.y, h0.z, h0.w, h1.x, h1.y, h1.z, h1.w};
        if (ok) {
            unsigned int u[4];
#pragma unroll
            for (int j = 0; j < 4; j++) {
                u[j] = (unsigned int)(unsigned short)bfb(hv[2 * j])
                     | ((unsigned int)(unsigned short)bfb(hv[2 * j + 1]) << 16);
            }
            *(uint4*)(hb2 + row * 64 + (c0 >> 1)) = make_uint4(u[0], u[1], u[2], u[3]);
        }
        float e_l = 0.f, e_r = 0.f;
#pragma unroll
        for (int j = 0; j < 8; j++) {
            e_l = fmaf(hv[j], al8[j], e_l);
            e_r = fmaf(hv[j], ar8[j], e_r);
        }
        e_l += __shfl_xor(e_l, 1); e_l += __shfl_xor(e_l, 2);
        e_r += __shfl_xor(e_r, 1); e_r += __shfl_xor(e_r, 2);
        if (ok && (lane & 3) == 0) {
            el[row * 4 + head] = e_l;
            er[row * 4 + head] = e_r;
            elmax = fmaxf(elmax, e_l);
        }
    }
    elmax = fmaxf(elmax, __shfl_xor(elmax, 16));
    elmax = fmaxf(elmax, __shfl_xor(elmax, 32));
    __syncthreads();
    if ((lane & 15) == 0 || (lane & 15) == 4 || (lane & 15) == 8 || (lane & 15) == 12) {
        if (elmax > -INFINITY) atomicMax(&smax[head], f2ord(elmax));
    }
    __syncthreads();
    if (t < 4) atomicMax(&gmax[t], smax[t]);
}

// ---------- fused: single-pass (bounded-max) softmax agg + bias + LN + ELU ----------
template <bool LAST>
__global__ __launch_bounds__(256) void agg_ln_kernel(const int* __restrict__ offs,
                                                     const int* __restrict__ esrc,
                                                     const float* __restrict__ el,
                                                     const float* __restrict__ er,
                                                     const unsigned int* __restrict__ hb2,
                                                     const float* __restrict__ params,
                                                     const unsigned int* __restrict__ gmax,
                                                     const unsigned int* __restrict__ flag,
                                                     unsigned int* __restrict__ x_next,
                                                     void* __restrict__ out) {
    int node = (blockIdx.x * 256 + threadIdx.x) >> 6;
    int lane = threadIdx.x & 63;
    if (node >= N_NODES) return;
    int e0 = offs[node], e1 = offs[node + 1];
    int d = e1 - e0;
    int sh = lane & 3;
    int slot = lane >> 2;
    float er_s = er[node * 4 + sh];
    float M = leaky(ord2f(gmax[sh]) + er_s);

    int hd = lane >> 4;
    int c0 = lane * 2;
    const unsigned int* hbl = hb2 + lane;   // hoisted lane base

    float lsum = 0.f;
    float a0e = 0.f, a1e = 0.f, a0o = 0.f, a1o = 0.f;  // dual chains
    for (int b0 = 0; b0 < d; b0 += 16) {
        int idx = b0 + slot;
        float ex = 0.f;
        int s = 0;
        if (idx < d) {
            s = esrc[e0 + idx];
            ex = __expf(leaky(el[s * 4 + sh] + er_s) - M);
        }
        lsum += ex;
        _Float16 e16 = (_Float16)ex;
        unsigned int pk = ((unsigned int)s << 16)
                        | (unsigned int)__builtin_bit_cast(unsigned short, e16);
        int nb = min(16, d - b0);
        if (nb == 16) {
#pragma unroll
            for (int j = 0; j < 16; j += 2) {
                unsigned int q0 = __shfl(pk, j * 4 + hd);
                unsigned int q1 = __shfl(pk, (j + 1) * 4 + hd);
                unsigned int p0 = hbl[(q0 >> 16) * 64];
                unsigned int p1 = hbl[(q1 >> 16) * 64];
                float ex0 = (float)__builtin_bit_cast(_Float16, (unsigned short)(q0 & 0xFFFFu));
                float ex1 = (float)__builtin_bit_cast(_Float16, (unsigned short)(q1 & 0xFFFFu));
                a0e = fmaf(ex0, u2f((unsigned short)(p0 & 0xFFFFu)), a0e);
                a1e = fmaf(ex0, __uint_as_float(p0 & 0xFFFF0000u), a1e);
                a0o = fmaf(ex1, u2f((unsigned short)(p1 & 0xFFFFu)), a0o);
                a1o = fmaf(ex1, __uint_as_float(p1 & 0xFFFF0000u), a1o);
            }
        } else {
            for (int j = 0; j < nb; ++j) {
                unsigned int q = __shfl(pk, j * 4 + hd);
                unsigned int p = hbl[(q >> 16) * 64];
                float exj = (float)__builtin_bit_cast(_Float16, (unsigned short)(q & 0xFFFFu));
                a0e = fmaf(exj, u2f((unsigned short)(p & 0xFFFFu)), a0e);
                a1e = fmaf(exj, __uint_as_float(p & 0xFFFF0000u), a1e);
            }
        }
    }
    float a0 = a0e + a0o, a1 = a1e + a1o;
#pragma unroll
    for (int off = 4; off <= 32; off <<= 1) lsum += __shfl_xor(lsum, off);
    float l = __shfl(lsum, hd);

    float inv = 1.f / fmaxf(l, 1e-9f);
    const float* b  = params + 16640;
    const float* g  = params + 16768;
    const float* be = params + 16896;
    float v0 = fmaf(a0, inv, b[c0]);
    float v1 = fmaf(a1, inv, b[c0 + 1]);

    float s = v0 + v1;
#pragma unroll
    for (int off = 32; off >= 1; off >>= 1) s += __shfl_xor(s, off);
    float mu = s * (1.f / 128.f);
    float q0 = v0 - mu, q1 = v1 - mu;
    float vs = q0 * q0 + q1 * q1;
#pragma unroll
    for (int off = 32; off >= 1; off >>= 1) vs += __shfl_xor(vs, off);
    float rstd = rsqrtf(vs * (1.f / 128.f) + LN_EPS);
    float y0 = q0 * rstd * g[c0] + be[c0];
    float y1 = q1 * rstd * g[c0 + 1] + be[c0 + 1];
    y0 = y0 > 0.f ? y0 : expm1f(y0);
    y1 = y1 > 0.f ? y1 : expm1f(y1);

    if (LAST) {
        if (*flag) {
            unsigned int packed = (unsigned int)(unsigned short)bfb(y0)
                                | ((unsigned int)(unsigned short)bfb(y1) << 16);
            ((unsigned int*)out)[node * 64 + lane] = packed;
        } else {
            ((float2*)out)[node * 64 + lane] = make_float2(y0, y1);
        }
    } else {
        unsigned int packed = (unsigned int)(unsigned short)bfb(y0)
                            | ((unsigned int)(unsigned short)bfb(y1) << 16);
        x_next[node * 64 + lane] = packed;
    }
}

extern "C" void kernel_launch(void* const* d_in, const int* in_sizes, int n_in,
                              void* d_out, int out_size, void* d_ws, size_t ws_size,
                              hipStream_t stream) {
    const void* features = d_in[0];
    const int* src = (const int*)d_in[1];
    const int* dst = (const int*)d_in[2];

    char* w = (char*)d_ws;
    unsigned int* xbuf = (unsigned int*)w;                 // 12.8 MB (layer-2 input, packed bf16)
    unsigned int* hb = (unsigned int*)(w + 12800000);      // 12.8 MB (h bf16 packed)
    float* el = (float*)(w + 25600000);                    // 800 KB
    float* er = (float*)(w + 26400000);                    // 800 KB
    float* params0 = (float*)(w + 27200000);               // 68 KB
    float* params1 = params0 + PARAM_FLOATS;               // 68 KB
    unsigned short* wt0 = (unsigned short*)(w + 27337000); // 32 KB
    unsigned short* wt1 = wt0 + 16384;                     // 32 KB
    int* offs = (int*)(w + 27403000);                      // 50001 ints
    int* esrc = (int*)(w + 27604000);                      // 800000 ints
    int* bcnt  = (int*)(w + 30804992);                     // 196 ints
    int* bbase = (int*)(w + 30806016);                     // 196 ints
    unsigned int* flag  = (unsigned int*)(w + 30806848);
    unsigned int* gmax0 = (unsigned int*)(w + 30806912);
    unsigned int* gmax1 = (unsigned int*)(w + 30806976);
    unsigned int* ebuf = (unsigned int*)(w + 30807040);    // 196*6144*4 = 4.8 MB

    detect_kernel<<<1, 256, 0, stream>>>((const unsigned int*)d_in[3], flag, gmax0, gmax1);
    cvt_params_kernel<<<(PARAM_FLOATS + 255) / 256, 256, 0, stream>>>(
        d_in[3], d_in[4], d_in[5], d_in[6], d_in[7], d_in[8], flag, params0, wt0);
    cvt_params_kernel<<<(PARAM_FLOATS + 255) / 256, 256, 0, stream>>>(
        d_in[9], d_in[10], d_in[11], d_in[12], d_in[13], d_in[14], flag, params1, wt1);

    hipMemsetAsync(bcnt, 0, NBUCK * sizeof(int), stream);
    bin_kernel<<<(E_EDGES + BIN_CH - 1) / BIN_CH, 256, 0, stream>>>(src, dst, bcnt, ebuf);
    bscan_kernel<<<1, 256, 0, stream>>>(bcnt, bbase);
    csr_kernel<<<NBUCK, 256, 0, stream>>>(bcnt, bbase, ebuf, offs, esrc);

    for (int l = 0; l < 2; ++l) {
        float* params = (l == 0) ? params0 : params1;
        unsigned short* wt = (l == 0) ? wt0 : wt1;
        unsigned int* gmax = (l == 0) ? gmax0 : gmax1;
        const void* x = (l == 0) ? features : (const void*)xbuf;
        int mode = (l == 0) ? 0 : 1;

        gemm_mfma_kernel<<<(N_NODES + 63) / 64, 256, 0, stream>>>(
            x, wt, params, flag, mode, hb, el, er, gmax, N_NODES);
        if (l == 0) {
            agg_ln_kernel<false><<<(N_NODES * 64 + 255) / 256, 256, 0, stream>>>(
                offs, esrc, el, er, hb, params, gmax, flag, xbuf, nullptr);
        } else {
            agg_ln_kernel<true><<<(N_NODES * 64 + 255) / 256, 256, 0, stream>>>(
                offs, esrc, el, er, hb, params, gmax, flag, nullptr, d_out);
        }
    }
}

// Round 13
// 288.818 us; speedup vs baseline: 1.1459x; 1.1459x over previous
//
#include <hip/hip_runtime.h>
#include <hip/hip_bf16.h>

#define N_NODES 50000
#define E_EDGES 800000
#define HID 128
#define HEADS 4
#define NEG_SLOPE 0.2f
#define LN_EPS 1e-5f
#define PARAM_FLOATS 17024  // [W region](16384) al(128) ar(128) b(128) g(128) be(128)
#define NBUCK 196           // buckets of 256 nodes
#define BCAP 6144           // max edges/bucket
#define BIN_CH 2048         // edges per bin block

typedef __attribute__((ext_vector_type(8))) short short8;
typedef __attribute__((ext_vector_type(4))) float float4v;

__device__ __forceinline__ float bf2f(__hip_bfloat16 b) { return __bfloat162float(b); }
__device__ __forceinline__ float u2f(unsigned short u) {
    return __uint_as_float(((unsigned int)u) << 16);
}
__device__ __forceinline__ short bfb(float f) {
    __hip_bfloat16 h = __float2bfloat16(f);
    return *(short*)&h;
}
__device__ __forceinline__ float leaky(float v) { return v > 0.f ? v : v * NEG_SLOPE; }

__device__ __forceinline__ unsigned int f2ord(float f) {
    unsigned int u = __float_as_uint(f);
    return (u & 0x80000000u) ? ~u : (u | 0x80000000u);
}
__device__ __forceinline__ float ord2f(unsigned int u) {
    u = (u & 0x80000000u) ? (u & 0x7FFFFFFFu) : ~u;
    return __uint_as_float(u);
}

// ---------- runtime dtype detection + gmax init ----------
__global__ __launch_bounds__(256) void detect_kernel(const unsigned int* __restrict__ w0,
                                                     unsigned int* __restrict__ flag,
                                                     unsigned int* __restrict__ gmax0,
                                                     unsigned int* __restrict__ gmax1) {
    int t = threadIdx.x;
    if (t < 4) {
        gmax0[t] = f2ord(-INFINITY);
        gmax1[t] = f2ord(-INFINITY);
    }
    int cnt = 0;
    for (int i = t; i < 4096; i += 256) {
        unsigned int lo = (w0[i] & 0xFFFFu) << 16;
        float v = fabsf(__uint_as_float(lo));
        if (v >= 1e-6f && v <= 1.0f) cnt++;
    }
    __shared__ int sh[4];
#pragma unroll
    for (int off = 32; off >= 1; off >>= 1) cnt += __shfl_xor(cnt, off);
    if ((t & 63) == 0) sh[t >> 6] = cnt;
    __syncthreads();
    if (t == 0) *flag = ((sh[0] + sh[1] + sh[2] + sh[3]) > 2048) ? 1u : 0u;
}

__device__ __forceinline__ float load_any(const void* p, int i, unsigned int isbf16) {
    return isbf16 ? bf2f(((const __hip_bfloat16*)p)[i]) : ((const float*)p)[i];
}

// params fp32 block (al/ar/b/g/be at 16384..17024) + Wt bf16 [n][k]
__global__ __launch_bounds__(256) void cvt_params_kernel(const void* W, const void* al,
                                                         const void* ar, const void* b,
                                                         const void* g, const void* be,
                                                         const unsigned int* __restrict__ flag,
                                                         float* __restrict__ out,
                                                         unsigned short* __restrict__ wt) {
    int i = blockIdx.x * 256 + threadIdx.x;
    if (i >= PARAM_FLOATS) return;
    unsigned int isb = *flag;
    if (i < 16384) {
        unsigned short bits;
        if (isb) bits = ((const unsigned short*)W)[i];
        else     { short s = bfb(((const float*)W)[i]); bits = (unsigned short)s; }
        wt[((i & 127) << 7) | (i >> 7)] = bits;  // Wt[n][k] = W[k][n]
        return;
    }
    const void* src; int off;
    if (i < 16512)      { src = al; off = i - 16384; }
    else if (i < 16640) { src = ar; off = i - 16512; }
    else if (i < 16768) { src = b;  off = i - 16640; }
    else if (i < 16896) { src = g;  off = i - 16768; }
    else                { src = be; off = i - 16896; }
    out[i] = load_any(src, off, isb);
}

// ---------- CSR build, phase 1: bin edges by dst>>8, packed (src<<8)|(dst&255) ----------
__global__ __launch_bounds__(256) void bin_kernel(const int* __restrict__ src,
                                                  const int* __restrict__ dst,
                                                  int* __restrict__ bcnt,
                                                  unsigned int* __restrict__ ebuf) {
    __shared__ int lh[NBUCK];
    __shared__ int lbase[NBUCK];
    int t = threadIdx.x;
    for (int i = t; i < NBUCK; i += 256) lh[i] = 0;
    __syncthreads();
    int e0 = blockIdx.x * BIN_CH;
    int n = min(BIN_CH, E_EDGES - e0);
    int s8[8], d8[8], rk[8];
#pragma unroll
    for (int j = 0; j < 8; ++j) {
        int k = j * 256 + t;
        if (k < n) {
            s8[j] = src[e0 + k];
            d8[j] = dst[e0 + k];
            rk[j] = atomicAdd(&lh[d8[j] >> 8], 1);
        }
    }
    __syncthreads();
    for (int i = t; i < NBUCK; i += 256) lbase[i] = atomicAdd(&bcnt[i], lh[i]);
    __syncthreads();
#pragma unroll
    for (int j = 0; j < 8; ++j) {
        int k = j * 256 + t;
        if (k < n) {
            int b = d8[j] >> 8;
            int pos = lbase[b] + rk[j];
            if (pos < BCAP)
                ebuf[b * BCAP + pos] = ((unsigned int)s8[j] << 8) | (unsigned int)(d8[j] & 255);
        }
    }
}

__global__ __launch_bounds__(256) void bscan_kernel(const int* __restrict__ bcnt,
                                                    int* __restrict__ bbase) {
    int t = threadIdx.x;
    int lane = t & 63, wid = t >> 6;
    int v = (t < NBUCK) ? min(bcnt[t], BCAP) : 0;
    int x = v;
#pragma unroll
    for (int o = 1; o < 64; o <<= 1) {
        int y = __shfl_up(x, o);
        if (lane >= o) x += y;
    }
    __shared__ int wt[4];
    if (lane == 63) wt[wid] = x;
    __syncthreads();
    int add = 0;
    for (int j = 0; j < wid; j++) add += wt[j];
    if (t < NBUCK) bbase[t] = add + x - v;  // exclusive
}

__global__ __launch_bounds__(256) void csr_kernel(const int* __restrict__ bcnt,
                                                  const int* __restrict__ bbase,
                                                  const unsigned int* __restrict__ ebuf,
                                                  int* __restrict__ offs,
                                                  int* __restrict__ esrc) {
    __shared__ int cnt[256];
    __shared__ int wt[4];
    __shared__ int out_lds[BCAP];
    int b = blockIdx.x, t = threadIdx.x;
    int n = min(bcnt[b], BCAP);
    int base = bbase[b];
    const unsigned int* eb = ebuf + b * BCAP;
    cnt[t] = 0;
    __syncthreads();
    for (int i = t; i < n; i += 256) atomicAdd(&cnt[eb[i] & 255u], 1);
    __syncthreads();
    int lane = t & 63, wid = t >> 6;
    int v = cnt[t];
    int x = v;
#pragma unroll
    for (int o = 1; o < 64; o <<= 1) {
        int y = __shfl_up(x, o);
        if (lane >= o) x += y;
    }
    if (lane == 63) wt[wid] = x;
    __syncthreads();
    int add = 0;
    for (int j = 0; j < wid; j++) add += wt[j];
    int excl = add + x - v;
    int node = b * 256 + t;
    if (node <= N_NODES) offs[node] = base + excl;
    __syncthreads();
    cnt[t] = excl;
    __syncthreads();
    for (int i = t; i < n; i += 256) {
        unsigned int e = eb[i];
        int p = atomicAdd(&cnt[e & 255u], 1);
        out_lds[p] = (int)(e >> 8);
    }
    __syncthreads();
    for (int i = t; i < n; i += 256) esrc[base + i] = out_lds[i];
}

// ---------- MFMA GEMM: h = x @ W -> bf16 h, el/er, per-head global el-max ----------
__global__ __launch_bounds__(256) void gemm_mfma_kernel(const void* __restrict__ xin,
                                                        const unsigned short* __restrict__ wt,
                                                        const float* __restrict__ params,
                                                        const unsigned int* __restrict__ flag,
                                                        int mode,
                                                        unsigned int* __restrict__ hb2,
                                                        float* __restrict__ el,
                                                        float* __restrict__ er,
                                                        unsigned int* __restrict__ gmax,
                                                        int M) {
    __shared__ float ldsC[4][16][132];
    __shared__ unsigned int smax[4];
    unsigned int isb = mode ? 1u : *flag;
    int t = threadIdx.x;
    if (t < 4) smax[t] = 0u;
    int w = t >> 6, lane = t & 63;
    int m = lane & 15, quad = lane >> 4;
    int row0b = blockIdx.x * 64;
    int arow = row0b + w * 16 + m;
    bool avalid = arow < M;

    float4v acc[8];
#pragma unroll
    for (int i = 0; i < 8; i++) acc[i] = (float4v){0.f, 0.f, 0.f, 0.f};

#pragma unroll
    for (int kt = 0; kt < 4; ++kt) {
        short8 a = (short8){0, 0, 0, 0, 0, 0, 0, 0};
        if (avalid) {
            int base = arow * 128 + kt * 32 + quad * 8;
            if (isb) {
                a = *(const short8*)((const unsigned short*)xin + base);
            } else {
                const float* xp = (const float*)xin + base;
                float4 f0 = *(const float4*)xp;
                float4 f1 = *(const float4*)(xp + 4);
                a = (short8){bfb(f0.x), bfb(f0.y), bfb(f0.z), bfb(f0.w),
                             bfb(f1.x), bfb(f1.y), bfb(f1.z), bfb(f1.w)};
            }
        }
#pragma unroll
        for (int ct = 0; ct < 8; ++ct) {
            short8 b = *(const short8*)(wt + (ct * 16 + m) * 128 + kt * 32 + quad * 8);
            acc[ct] = __builtin_amdgcn_mfma_f32_16x16x32_bf16(a, b, acc[ct], 0, 0, 0);
        }
    }

#pragma unroll
    for (int ct = 0; ct < 8; ++ct)
#pragma unroll
        for (int r = 0; r < 4; ++r)
            ldsC[w][quad * 4 + r][ct * 16 + m] = acc[ct][r];
    __syncthreads();

    int c0 = (t & 15) * 8;
    int r0e = (t >> 4) * 4;
    float al8[8], ar8[8];
#pragma unroll
    for (int j = 0; j < 8; j++) {
        al8[j] = params[16384 + c0 + j];
        ar8[j] = params[16512 + c0 + j];
    }
    int head = (lane & 15) >> 2;
    float elmax = -INFINITY;

#pragma unroll
    for (int i = 0; i < 4; i++) {
        int rr = r0e + i;
        int row = row0b + rr;
        bool ok = row < M;
        const float* ld = &ldsC[rr >> 4][rr & 15][c0];
        float4 h0 = *(const float4*)ld;
        float4 h1 = *(const float4*)(ld + 4);
        float hv[8] = {h0.x, h0.y, h0.z, h0.w, h1.x, h1.y, h1.z, h1.w};
        if (ok) {
            unsigned int u[4];
#pragma unroll
            for (int j = 0; j < 4; j++) {
                u[j] = (unsigned int)(unsigned short)bfb(hv[2 * j])
                     | ((unsigned int)(unsigned short)bfb(hv[2 * j + 1]) << 16);
            }
            *(uint4*)(hb2 + row * 64 + (c0 >> 1)) = make_uint4(u[0], u[1], u[2], u[3]);
        }
        float e_l = 0.f, e_r = 0.f;
#pragma unroll
        for (int j = 0; j < 8; j++) {
            e_l = fmaf(hv[j], al8[j], e_l);
            e_r = fmaf(hv[j], ar8[j], e_r);
        }
        e_l += __shfl_xor(e_l, 1); e_l += __shfl_xor(e_l, 2);
        e_r += __shfl_xor(e_r, 1); e_r += __shfl_xor(e_r, 2);
        if (ok && (lane & 3) == 0) {
            el[row * 4 + head] = e_l;
            er[row * 4 + head] = e_r;
            elmax = fmaxf(elmax, e_l);
        }
    }
    elmax = fmaxf(elmax, __shfl_xor(elmax, 16));
    elmax = fmaxf(elmax, __shfl_xor(elmax, 32));
    __syncthreads();
    if ((lane & 15) == 0 || (lane & 15) == 4 || (lane & 15) == 8 || (lane & 15) == 12) {
        if (elmax > -INFINITY) atomicMax(&smax[head], f2ord(elmax));
    }
    __syncthreads();
    if (t < 4) atomicMax(&gmax[t], smax[t]);
}

// ---------- fused: single-pass (bounded-max) softmax agg + bias + LN + ELU ----------
// Reverted to the Round-11 body (32 VGPR / ~62% occupancy — R12's dual chains cost
// 44 VGPR and dropped occupancy to 41%, regressing 52->75 µs).
template <bool LAST>
__global__ __launch_bounds__(256) void agg_ln_kernel(const int* __restrict__ offs,
                                                     const int* __restrict__ esrc,
                                                     const float* __restrict__ el,
                                                     const float* __restrict__ er,
                                                     const unsigned int* __restrict__ hb2,
                                                     const float* __restrict__ params,
                                                     const unsigned int* __restrict__ gmax,
                                                     const unsigned int* __restrict__ flag,
                                                     unsigned int* __restrict__ x_next,
                                                     void* __restrict__ out) {
    int node = (blockIdx.x * 256 + threadIdx.x) >> 6;
    int lane = threadIdx.x & 63;
    if (node >= N_NODES) return;
    int e0 = offs[node], e1 = offs[node + 1];
    int d = e1 - e0;
    int sh = lane & 3;
    int slot = lane >> 2;
    float er_s = er[node * 4 + sh];
    float M = leaky(ord2f(gmax[sh]) + er_s);

    int hd = lane >> 4;
    int c0 = lane * 2;

    float lsum = 0.f, a0 = 0.f, a1 = 0.f;
    for (int b0 = 0; b0 < d; b0 += 16) {
        int idx = b0 + slot;
        float ex = 0.f;
        int s = 0;
        if (idx < d) {
            s = esrc[e0 + idx];
            ex = __expf(leaky(el[s * 4 + sh] + er_s) - M);
        }
        lsum += ex;
        _Float16 e16 = (_Float16)ex;
        unsigned int pk = ((unsigned int)s << 16)
                        | (unsigned int)__builtin_bit_cast(unsigned short, e16);
        int nb = min(16, d - b0);
        if (nb == 16) {
#pragma unroll
            for (int j = 0; j < 16; ++j) {
                unsigned int q = __shfl(pk, j * 4 + hd);
                int sj = q >> 16;
                float exj = (float)__builtin_bit_cast(_Float16, (unsigned short)(q & 0xFFFFu));
                unsigned int p = hb2[sj * 64 + lane];
                a0 = fmaf(exj, u2f((unsigned short)(p & 0xFFFFu)), a0);
                a1 = fmaf(exj, __uint_as_float(p & 0xFFFF0000u), a1);
            }
        } else {
            for (int j = 0; j < nb; ++j) {
                unsigned int q = __shfl(pk, j * 4 + hd);
                int sj = q >> 16;
                float exj = (float)__builtin_bit_cast(_Float16, (unsigned short)(q & 0xFFFFu));
                unsigned int p = hb2[sj * 64 + lane];
                a0 = fmaf(exj, u2f((unsigned short)(p & 0xFFFFu)), a0);
                a1 = fmaf(exj, __uint_as_float(p & 0xFFFF0000u), a1);
            }
        }
    }
#pragma unroll
    for (int off = 4; off <= 32; off <<= 1) lsum += __shfl_xor(lsum, off);
    float l = __shfl(lsum, hd);

    float inv = 1.f / fmaxf(l, 1e-9f);
    const float* b  = params + 16640;
    const float* g  = params + 16768;
    const float* be = params + 16896;
    float v0 = fmaf(a0, inv, b[c0]);
    float v1 = fmaf(a1, inv, b[c0 + 1]);

    float s = v0 + v1;
#pragma unroll
    for (int off = 32; off >= 1; off >>= 1) s += __shfl_xor(s, off);
    float mu = s * (1.f / 128.f);
    float q0 = v0 - mu, q1 = v1 - mu;
    float vs = q0 * q0 + q1 * q1;
#pragma unroll
    for (int off = 32; off >= 1; off >>= 1) vs += __shfl_xor(vs, off);
    float rstd = rsqrtf(vs * (1.f / 128.f) + LN_EPS);
    float y0 = q0 * rstd * g[c0] + be[c0];
    float y1 = q1 * rstd * g[c0 + 1] + be[c0 + 1];
    y0 = y0 > 0.f ? y0 : expm1f(y0);
    y1 = y1 > 0.f ? y1 : expm1f(y1);

    if (LAST) {
        if (*flag) {
            unsigned int packed = (unsigned int)(unsigned short)bfb(y0)
                                | ((unsigned int)(unsigned short)bfb(y1) << 16);
            ((unsigned int*)out)[node * 64 + lane] = packed;
        } else {
            ((float2*)out)[node * 64 + lane] = make_float2(y0, y1);
        }
    } else {
        unsigned int packed = (unsigned int)(unsigned short)bfb(y0)
                            | ((unsigned int)(unsigned short)bfb(y1) << 16);
        x_next[node * 64 + lane] = packed;
    }
}

extern "C" void kernel_launch(void* const* d_in, const int* in_sizes, int n_in,
                              void* d_out, int out_size, void* d_ws, size_t ws_size,
                              hipStream_t stream) {
    const void* features = d_in[0];
    const int* src = (const int*)d_in[1];
    const int* dst = (const int*)d_in[2];

    char* w = (char*)d_ws;
    unsigned int* xbuf = (unsigned int*)w;                 // 12.8 MB (layer-2 input, packed bf16)
    unsigned int* hb = (unsigned int*)(w + 12800000);      // 12.8 MB (h bf16 packed)
    float* el = (float*)(w + 25600000);                    // 800 KB
    float* er = (float*)(w + 26400000);                    // 800 KB
    float* params0 = (float*)(w + 27200000);               // 68 KB
    float* params1 = params0 + PARAM_FLOATS;               // 68 KB
    unsigned short* wt0 = (unsigned short*)(w + 27337000); // 32 KB
    unsigned short* wt1 = wt0 + 16384;                     // 32 KB
    int* offs = (int*)(w + 27403000);                      // 50001 ints
    int* esrc = (int*)(w + 27604000);                      // 800000 ints
    int* bcnt  = (int*)(w + 30804992);                     // 196 ints
    int* bbase = (int*)(w + 30806016);                     // 196 ints
    unsigned int* flag  = (unsigned int*)(w + 30806848);
    unsigned int* gmax0 = (unsigned int*)(w + 30806912);
    unsigned int* gmax1 = (unsigned int*)(w + 30806976);
    unsigned int* ebuf = (unsigned int*)(w + 30807040);    // 196*6144*4 = 4.8 MB

    detect_kernel<<<1, 256, 0, stream>>>((const unsigned int*)d_in[3], flag, gmax0, gmax1);
    cvt_params_kernel<<<(PARAM_FLOATS + 255) / 256, 256, 0, stream>>>(
        d_in[3], d_in[4], d_in[5], d_in[6], d_in[7], d_in[8], flag, params0, wt0);
    cvt_params_kernel<<<(PARAM_FLOATS + 255) / 256, 256, 0, stream>>>(
        d_in[9], d_in[10], d_in[11], d_in[12], d_in[13], d_in[14], flag, params1, wt1);

    hipMemsetAsync(bcnt, 0, NBUCK * sizeof(int), stream);
    bin_kernel<<<(E_EDGES + BIN_CH - 1) / BIN_CH, 256, 0, stream>>>(src, dst, bcnt, ebuf);
    bscan_kernel<<<1, 256, 0, stream>>>(bcnt, bbase);
    csr_kernel<<<NBUCK, 256, 0, stream>>>(bcnt, bbase, ebuf, offs, esrc);

    for (int l = 0; l < 2; ++l) {
        float* params = (l == 0) ? params0 : params1;
        unsigned short* wt = (l == 0) ? wt0 : wt1;
        unsigned int* gmax = (l == 0) ? gmax0 : gmax1;
        const void* x = (l == 0) ? features : (const void*)xbuf;
        int mode = (l == 0) ? 0 : 1;

        gemm_mfma_kernel<<<(N_NODES + 63) / 64, 256, 0, stream>>>(
            x, wt, params, flag, mode, hb, el, er, gmax, N_NODES);
        if (l == 0) {
            agg_ln_kernel<false><<<(N_NODES * 64 + 255) / 256, 256, 0, stream>>>(
                offs, esrc, el, er, hb, params, gmax, flag, xbuf, nullptr);
        } else {
            agg_ln_kernel<true><<<(N_NODES * 64 + 255) / 256, 256, 0, stream>>>(
                offs, esrc, el, er, hb, params, gmax, flag, nullptr, d_out);
        }
    }
}